// Round 5
// baseline (691.905 us; speedup 1.0000x reference)
//
#include <hip/hip_runtime.h>

#define CH 256
#define KC 8192
#define NT 32768

#define TM 128         // tokens per block (A persistent in LDS)
#define TN 128         // codes per jt tile
#define BK 32          // channels per stage
#define NSTG ((KC / TN) * (CH / BK))   // 64 jt * 8 cc = 512 stages

typedef _Float16 half4_t __attribute__((ext_vector_type(4)));
typedef _Float16 half8_t __attribute__((ext_vector_type(8)));
typedef float floatx4 __attribute__((ext_vector_type(4)));

typedef __attribute__((address_space(1))) const unsigned int guint_t;
typedef __attribute__((address_space(3))) unsigned int luint_t;

// XOR-swizzled LDS offset (halves) for row-major [row][BK] tiles, 16B chunks.
// Proven 0 bank conflicts in the round-3 measurement.
__device__ __forceinline__ int swz(int row, int chunk) {
    return row * BK + ((chunk ^ ((row >> 1) & 3)) << 3);
}

// ---------------------------------------------------------------------------
// Kernel 1 (fused prep):
//  blocks [0, KC):   codebook row -> fp16 hi/lo + cbsq, zero hist
//  blocks [KC, ...): split embeddings fp32 -> fp16 hi/lo (1 float4/thread)
// ---------------------------------------------------------------------------
__global__ void k_prep(const float* __restrict__ usage,
                       const float* __restrict__ ces,
                       const float* __restrict__ emb,
                       _Float16* __restrict__ cbh,
                       _Float16* __restrict__ cbl,
                       float* __restrict__ cbsq,
                       _Float16* __restrict__ eh,
                       _Float16* __restrict__ el,
                       int* __restrict__ hist) {
    int b = blockIdx.x, t = threadIdx.x;
    if (b < KC) {
        float uc = fmaxf(usage[b], 1e-5f);
        float v  = ces[b * CH + t];
        float cb = v / uc;
        _Float16 h = (_Float16)cb;
        cbh[b * CH + t] = h;
        cbl[b * CH + t] = (_Float16)(cb - (float)h);

        float p = cb * cb;
        #pragma unroll
        for (int off = 32; off; off >>= 1) p += __shfl_down(p, off);
        __shared__ float ps[4];
        int lane = t & 63, w = t >> 6;
        if (lane == 0) ps[w] = p;
        __syncthreads();
        if (t == 0) cbsq[b] = ps[0] + ps[1] + ps[2] + ps[3];
        if (t == 1) hist[b] = 0;
    } else {
        int i = (b - KC) * 256 + t;      // float4 index
        float4 v = ((const float4*)emb)[i];
        float va[4] = {v.x, v.y, v.z, v.w};
        half4_t h, l;
        #pragma unroll
        for (int q = 0; q < 4; ++q) {
            _Float16 hh = (_Float16)va[q];
            h[q] = hh;
            l[q] = (_Float16)(va[q] - (float)hh);
        }
        ((half4_t*)eh)[i] = h;
        ((half4_t*)el)[i] = l;
    }
}

// ---------------------------------------------------------------------------
// Kernel 2: fp16-split MFMA argmin — barrier-free, 2 waves/SIMD, B in regs.
// 8 waves/block (512 thr), wave tile = 64 tokens x 32 codes (round-3
// decomposition). A (128 KiB hi+lo) LDS-persistent with the round-3
// XOR-swizzled layout (0 conflicts). B NEVER touches LDS: each wave loads
// its own fragments straight to a register double-buffer (4 x
// global_load_dwordx4 per stage, issued one stage ahead; the compiler's
// per-register vmcnt tracking provides counted waits). No cross-wave
// production in the loop -> zero barriers; 2 waves/SIMD give TLP to fill
// MFMA issue gaps. LDS pipe now carries only A fragments (64 reads/stage/CU).
// ---------------------------------------------------------------------------
__launch_bounds__(512, 1)
__global__ void k_argmin(const _Float16* __restrict__ eh,
                         const _Float16* __restrict__ el,
                         const _Float16* __restrict__ cbh,
                         const _Float16* __restrict__ cbl,
                         const float* __restrict__ cbsq,
                         unsigned long long* __restrict__ packed) {
    __shared__ __align__(16) unsigned char smraw[135168];  // 128K A + 4K cand
    _Float16* smA = (_Float16*)smraw;     // [hl][cc8][swz(128x32)] halves

    const int t    = threadIdx.x;
    const int lane = t & 63;
    const int wave = t >> 6;          // 0..7
    const int wx   = wave & 3;        // code quarter (32 codes)
    const int wy   = wave >> 2;       // token half (64 tokens)
    const int lr   = lane & 15;
    const int koq  = lane >> 4;       // k-chunk (quad) for fragments

    const int n0 = blockIdx.x * TM;

    // A-DMA lane mapping with inverse swizzle pre-applied (round-3 proven):
    // q = (lane&3) ^ ((lane>>3)&3), row-within-issue = lane>>2.
    const int qsw  = (lane & 3) ^ ((lane >> 3) & 3);
    const int lrow = lane >> 2;

    float minv[16];
    int   mini[16];
    #pragma unroll
    for (int e = 0; e < 16; ++e) { minv[e] = 3.402823466e38f; mini[e] = 0; }

    floatx4 acc[4][2];
    #pragma unroll
    for (int mf = 0; mf < 4; ++mf) {
        acc[mf][0] = (floatx4){0.f, 0.f, 0.f, 0.f};
        acc[mf][1] = (floatx4){0.f, 0.f, 0.f, 0.f};
    }

    // ---- prologue: A tile -> LDS once (8 waves cover [2 hl][8 cc]) ----
    {
        const int hl  = wave >> 2;
        const int ccb = (wave & 3) * 2;
        const _Float16* a_hl = hl ? el : eh;
        #pragma unroll
        for (int d = 0; d < 2; ++d) {
            const int cc = ccb + d;
            const _Float16* g0 = a_hl + (size_t)(n0 + lrow) * CH + cc * BK
                               + qsw * 8;
            #pragma unroll
            for (int i = 0; i < 8; ++i) {
                __builtin_amdgcn_global_load_lds(
                    (guint_t*)(g0 + (size_t)(i * 16) * CH),
                    (luint_t*)&smA[hl * 32768 + cc * 4096 + i * 512],
                    16, 0, 0);
            }
        }
    }
    asm volatile("s_waitcnt vmcnt(0)" ::: "memory");
    __syncthreads();   // A visible to all waves; the ONLY pre-loop barrier

    // B fragment loader: global -> regs, per-lane MFMA fragment addressing
    // (row = code, 16B k-chunk). Same request pattern the round-3 DMA
    // sustained from L2.
    auto loadB = [&](half8_t* bh, half8_t* bl, int sg) {
        const int c0 = (sg & 7) * BK;
        const int jb = (sg >> 3) * TN + wx * 32 + lr;
        const _Float16* gh = cbh + (size_t)jb * CH + c0 + koq * 8;
        const _Float16* gl = cbl + (size_t)jb * CH + c0 + koq * 8;
        bh[0] = *(const half8_t*)gh;
        bh[1] = *(const half8_t*)(gh + 16 * CH);
        bl[0] = *(const half8_t*)gl;
        bl[1] = *(const half8_t*)(gl + 16 * CH);
    };
    // A fragment loader: LDS -> regs, swizzled offsets (0 conflicts).
    auto loadA = [&](half8_t* ah, half8_t* al, int sg) {
        const int cc = sg & 7;
        #pragma unroll
        for (int mf = 0; mf < 4; ++mf) {
            int off = cc * 4096 + swz(wy * 64 + mf * 16 + lr, koq);
            ah[mf] = *(const half8_t*)&smA[off];
            al[mf] = *(const half8_t*)&smA[32768 + off];
        }
    };

    // register double-buffers (all indices static)
    half8_t fah[2][4], fal[2][4], fbh[2][2], fbl[2][2];
    float csq0 = 0.f, csq1 = 0.f;

    loadB(fbh[0], fbl[0], 0);
    loadA(fah[0], fal[0], 0);

#define SUBITER(S_, FC, FN)                                                  \
  {                                                                          \
    const int S = (S_);                                                      \
    if (S + 1 < NSTG) loadB(fbh[FN], fbl[FN], S + 1);                        \
    if ((S & 7) == 0) {                                                      \
      const int jb0 = (S >> 3) * TN + wx * 32 + lr;                          \
      csq0 = cbsq[jb0];                                                      \
      csq1 = cbsq[jb0 + 16];                                                 \
    }                                                                        \
    if (S + 1 < NSTG) loadA(fah[FN], fal[FN], S + 1);                        \
    _Pragma("unroll")                                                        \
    for (int mf = 0; mf < 4; ++mf) {                                         \
      acc[mf][0] = __builtin_amdgcn_mfma_f32_16x16x32_f16(                   \
          fah[FC][mf], fbh[FC][0], acc[mf][0], 0, 0, 0);                     \
      acc[mf][1] = __builtin_amdgcn_mfma_f32_16x16x32_f16(                   \
          fah[FC][mf], fbh[FC][1], acc[mf][1], 0, 0, 0);                     \
    }                                                                        \
    _Pragma("unroll")                                                        \
    for (int mf = 0; mf < 4; ++mf) {                                         \
      acc[mf][0] = __builtin_amdgcn_mfma_f32_16x16x32_f16(                   \
          fah[FC][mf], fbl[FC][0], acc[mf][0], 0, 0, 0);                     \
      acc[mf][1] = __builtin_amdgcn_mfma_f32_16x16x32_f16(                   \
          fah[FC][mf], fbl[FC][1], acc[mf][1], 0, 0, 0);                     \
    }                                                                        \
    _Pragma("unroll")                                                        \
    for (int mf = 0; mf < 4; ++mf) {                                         \
      acc[mf][0] = __builtin_amdgcn_mfma_f32_16x16x32_f16(                   \
          fal[FC][mf], fbh[FC][0], acc[mf][0], 0, 0, 0);                     \
      acc[mf][1] = __builtin_amdgcn_mfma_f32_16x16x32_f16(                   \
          fal[FC][mf], fbh[FC][1], acc[mf][1], 0, 0, 0);                     \
    }                                                                        \
    if ((S & 7) == 7) {                                                      \
      const int jb7 = (S >> 3) * TN + wx * 32 + lr;                          \
      _Pragma("unroll")                                                      \
      for (int mf = 0; mf < 4; ++mf) {                                       \
        _Pragma("unroll")                                                    \
        for (int r = 0; r < 4; ++r) {                                        \
          const int e = mf * 4 + r;                                          \
          float s0 = csq0 - 2.0f * acc[mf][0][r];                            \
          float s1 = csq1 - 2.0f * acc[mf][1][r];                            \
          float sv = s0; int si = jb7;                                       \
          if (s1 < sv) { sv = s1; si = jb7 + 16; }                           \
          if (sv < minv[e]) { minv[e] = sv; mini[e] = si; }                  \
          acc[mf][0][r] = 0.f;                                               \
          acc[mf][1][r] = 0.f;                                               \
        }                                                                    \
      }                                                                      \
    }                                                                        \
  }

    #pragma unroll 1
    for (int sp = 0; sp < NSTG; sp += 2) {
        SUBITER(sp,     0, 1);
        SUBITER(sp + 1, 1, 0);
    }
#undef SUBITER

    // ---- epilogue: cross-lane argmin, then cross-wave via LDS ----
    float* cand_v = (float*)(smraw + 131072);           // [4][128]
    int*   cand_i = (int*)(smraw + 131072 + 2048);      // [4][128]

    #pragma unroll
    for (int e = 0; e < 16; ++e) {
        float v = minv[e];
        int   x = mini[e];
        #pragma unroll
        for (int m = 1; m <= 8; m <<= 1) {
            float ov = __shfl_xor(v, m, 64);
            int   ox = __shfl_xor(x, m, 64);
            if (ov < v || (ov == v && ox < x)) { v = ov; x = ox; }
        }
        if (lr == 0) {
            int row = wy * 64 + (e >> 2) * 16 + (lane >> 4) * 4 + (e & 3);
            cand_v[wx * TM + row] = v;
            cand_i[wx * TM + row] = x;
        }
    }
    __syncthreads();

    if (t < TM) {
        float v0 = cand_v[t];          int i0 = cand_i[t];
        #pragma unroll
        for (int q = 1; q < 4; ++q) {
            float v1 = cand_v[q * TM + t]; int i1 = cand_i[q * TM + t];
            if (v1 < v0 || (v1 == v0 && i1 < i0)) { v0 = v1; i0 = i1; }
        }
        unsigned sb = __float_as_uint(v0);
        sb = (sb & 0x80000000u) ? ~sb : (sb | 0x80000000u);
        packed[n0 + t] = ((unsigned long long)sb << 32) | (unsigned)i0;
    }
}

// ---------------------------------------------------------------------------
// Kernel 3: gather + straight-through + loss partials + histogram
// ---------------------------------------------------------------------------
__global__ void k_gather(const float* __restrict__ emb,
                         const float* __restrict__ ces,
                         const float* __restrict__ usage,
                         const unsigned long long* __restrict__ packed,
                         float* __restrict__ out_eq,
                         float* __restrict__ codes_f,
                         int* __restrict__ hist,
                         float* __restrict__ partials) {
    int t = threadIdx.x;
    int wave = t >> 6, lane = t & 63;
    int n = blockIdx.x * 4 + wave;
    int k = (int)(packed[n] & 0xFFFFFFFFull);
    float uc = fmaxf(usage[k], 1e-5f);
    int c = lane * 4;

    float4 e = *(const float4*)&emb[(size_t)n * CH + c];
    float4 v = *(const float4*)&ces[(size_t)k * CH + c];
    float ea[4] = {e.x, e.y, e.z, e.w};
    float va[4] = {v.x, v.y, v.z, v.w};
    float eqa[4];
    float p = 0.0f;
    #pragma unroll
    for (int q = 0; q < 4; ++q) {
        float cb = va[q] / uc;
        float eq = ea[q] + (cb - ea[q]);
        eqa[q] = eq;
        float d = eq - ea[q];
        p += d * d;
    }
    *(float4*)&out_eq[(size_t)n * CH + c] =
        (float4){eqa[0], eqa[1], eqa[2], eqa[3]};

    #pragma unroll
    for (int off = 32; off; off >>= 1) p += __shfl_down(p, off);
    __shared__ float ps[4];
    if (lane == 0) {
        ps[wave] = p;
        codes_f[n] = (float)k;
        atomicAdd(&hist[k], 1);
    }
    __syncthreads();
    if (t == 0) partials[blockIdx.x] = ps[0] + ps[1] + ps[2] + ps[3];
}

// ---------------------------------------------------------------------------
// Kernel 4: exclusive prefix sum over hist -> offs, cursor (1 block)
// ---------------------------------------------------------------------------
__global__ void k_scan(const int* __restrict__ hist,
                       int* __restrict__ offs,
                       int* __restrict__ cursor) {
    __shared__ int bs[256];
    int t = threadIdx.x;
    int base = t * 32;
    int loc[32];
    int s = 0;
    #pragma unroll
    for (int i = 0; i < 32; ++i) { loc[i] = s; s += hist[base + i]; }
    int mysum = s;
    bs[t] = s;
    __syncthreads();
    for (int off = 1; off < 256; off <<= 1) {
        int v = (t >= off) ? bs[t - off] : 0;
        __syncthreads();
        bs[t] += v;
        __syncthreads();
    }
    int excl = bs[t] - mysum;
    #pragma unroll
    for (int i = 0; i < 32; ++i) {
        int o = excl + loc[i];
        offs[base + i]   = o;
        cursor[base + i] = o;
    }
}

// ---------------------------------------------------------------------------
// Kernel 5: scatter token ids into code-sorted buckets
// ---------------------------------------------------------------------------
__global__ void k_scatter(const unsigned long long* __restrict__ packed,
                          int* __restrict__ cursor,
                          int* __restrict__ bucket) {
    int n = blockIdx.x * 256 + threadIdx.x;
    int k = (int)(packed[n] & 0xFFFFFFFFull);
    int pos = atomicAdd(&cursor[k], 1);
    bucket[pos] = n;
}

// ---------------------------------------------------------------------------
// Kernel 6: per-code EMA (one BLOCK per code: coalesced 1KB row loads,
// thread t owns channel t, no atomics, no wave-serial latency chain)
// ---------------------------------------------------------------------------
__global__ void k_ema(const float* __restrict__ emb,
                      const float* __restrict__ ces,
                      const float* __restrict__ usage,
                      const int* __restrict__ hist,
                      const int* __restrict__ offs,
                      const int* __restrict__ bucket,
                      float* __restrict__ out_ces,
                      float* __restrict__ out_usage) {
    const float s = 0.01f;
    const float oms = 1.0f - s;
    int k = blockIdx.x, t = threadIdx.x;
    int start = offs[k], cnt = hist[k];
    float sum = 0.0f;
    #pragma unroll 2
    for (int i = 0; i < cnt; ++i) {
        int n = bucket[start + i];            // block-uniform (scalar) load
        sum += emb[(size_t)n * CH + t];       // coalesced row
    }
    out_ces[(size_t)k * CH + t] = oms * ces[(size_t)k * CH + t] + s * sum;
    if (t == 0) out_usage[k] = oms * usage[k] + s * (float)cnt;
}

// ---------------------------------------------------------------------------
// Kernel 7: reduce loss partials, mean over 2^23 elements
// ---------------------------------------------------------------------------
__global__ void k_final(const float* __restrict__ partials,
                        float* __restrict__ out_loss) {
    int t = threadIdx.x;
    float p = 0.0f;
    for (int i = t; i < NT / 4; i += 256) p += partials[i];
    #pragma unroll
    for (int off = 32; off; off >>= 1) p += __shfl_down(p, off);
    __shared__ float ps[4];
    if ((t & 63) == 0) ps[t >> 6] = p;
    __syncthreads();
    if (t == 0)
        out_loss[0] = (ps[0] + ps[1] + ps[2] + ps[3]) * (1.0f / 8388608.0f);
}

extern "C" void kernel_launch(void* const* d_in, const int* in_sizes, int n_in,
                              void* d_out, int out_size, void* d_ws, size_t ws_size,
                              hipStream_t stream) {
    const float* emb   = (const float*)d_in[0];  // [32768, 256]
    const float* usage = (const float*)d_in[1];  // [8192]
    const float* ces   = (const float*)d_in[2];  // [8192, 256]

    float* out      = (float*)d_out;
    float* o_codes  = out;                       // 32768
    float* o_eq     = out + NT;                  // 8388608
    float* o_loss   = o_eq + (size_t)NT * CH;    // 1
    float* o_usage  = o_loss + 1;                // 8192
    float* o_ces    = o_usage + KC;              // 2097152

    unsigned long long* packed = (unsigned long long*)d_ws;   // NT u64
    float* cbsq     = (float*)(packed + NT);                  // KC
    float* partials = cbsq + KC;                              // NT/4
    int* hist   = (int*)(partials + NT / 4);                  // KC
    int* offs   = hist + KC;                                  // KC
    int* cursor = offs + KC;                                  // KC
    int* bucket = cursor + KC;                                // NT
    _Float16* eh  = (_Float16*)(bucket + NT);                 // NT*CH
    _Float16* el  = eh + (size_t)NT * CH;
    _Float16* cbh = el + (size_t)NT * CH;                     // KC*CH
    _Float16* cbl = cbh + (size_t)KC * CH;

    k_prep<<<KC + NT * CH / 1024, 256, 0, stream>>>(
        usage, ces, emb, cbh, cbl, cbsq, eh, el, hist);
    k_argmin<<<NT / TM, 512, 0, stream>>>(eh, el, cbh, cbl, cbsq, packed);
    k_gather<<<NT / 4, 256, 0, stream>>>(emb, ces, usage, packed, o_eq,
                                         o_codes, hist, partials);
    k_scan<<<1, 256, 0, stream>>>(hist, offs, cursor);
    k_scatter<<<NT / 256, 256, 0, stream>>>(packed, cursor, bucket);
    k_ema<<<KC, 256, 0, stream>>>(emb, ces, usage, hist, offs, bucket,
                                  o_ces, o_usage);
    k_final<<<1, 256, 0, stream>>>(partials, o_loss);
}

// Round 6
// 668.813 us; speedup vs baseline: 1.0345x; 1.0345x over previous
//
#include <hip/hip_runtime.h>

#define CH 256
#define KC 8192
#define NT 32768

#define TM 128         // tokens per block (A persistent in LDS)
#define TN 256         // codes per jt tile (4 waves x 64)
#define BK 16          // channels per B stage
#define NSTG ((KC / TN) * (CH / BK))   // 32 jt * 16 cc = 512 stages

typedef _Float16 half4_t __attribute__((ext_vector_type(4)));
typedef _Float16 half8_t __attribute__((ext_vector_type(8)));
typedef float floatx16 __attribute__((ext_vector_type(16)));

typedef __attribute__((address_space(1))) const unsigned int guint_t;
typedef __attribute__((address_space(3))) unsigned int luint_t;

// ---------------------------------------------------------------------------
// Kernel 1 (fused prep):
//  blocks [0, KC):   codebook row -> fp16 hi/lo + cbsq, zero hist
//  blocks [KC, ...): split embeddings fp32 -> fp16 hi/lo (1 float4/thread)
// ---------------------------------------------------------------------------
__global__ void k_prep(const float* __restrict__ usage,
                       const float* __restrict__ ces,
                       const float* __restrict__ emb,
                       _Float16* __restrict__ cbh,
                       _Float16* __restrict__ cbl,
                       float* __restrict__ cbsq,
                       _Float16* __restrict__ eh,
                       _Float16* __restrict__ el,
                       int* __restrict__ hist) {
    int b = blockIdx.x, t = threadIdx.x;
    if (b < KC) {
        float uc = fmaxf(usage[b], 1e-5f);
        float v  = ces[b * CH + t];
        float cb = v / uc;
        _Float16 h = (_Float16)cb;
        cbh[b * CH + t] = h;
        cbl[b * CH + t] = (_Float16)(cb - (float)h);

        float p = cb * cb;
        #pragma unroll
        for (int off = 32; off; off >>= 1) p += __shfl_down(p, off);
        __shared__ float ps[4];
        int lane = t & 63, w = t >> 6;
        if (lane == 0) ps[w] = p;
        __syncthreads();
        if (t == 0) cbsq[b] = ps[0] + ps[1] + ps[2] + ps[3];
        if (t == 1) hist[b] = 0;
    } else {
        int i = (b - KC) * 256 + t;      // float4 index
        float4 v = ((const float4*)emb)[i];
        float va[4] = {v.x, v.y, v.z, v.w};
        half4_t h, l;
        #pragma unroll
        for (int q = 0; q < 4; ++q) {
            _Float16 hh = (_Float16)va[q];
            h[q] = hh;
            l[q] = (_Float16)(va[q] - (float)hh);
        }
        ((half4_t*)eh)[i] = h;
        ((half4_t*)el)[i] = l;
    }
}

// ---------------------------------------------------------------------------
// Kernel 2: fp16-split argmin with 32x32x16 MFMA.
// Round-3 skeleton (best measured): A (128 tok x 256 ch, hi+lo = 128 KiB)
// LDS-persistent; B streamed cross-wave via global_load_lds, double-buffered
// (2 x 16 KiB, BK=16), one rendezvous per stage. New core:
//  * mfma_f32_32x32x16_f16 (8.07 vs 9.7 cyc per unit work, half the instrs)
//  * wave tile 64 tok x 64 codes (acc[2][2] f32x16): 8 LDS reads / 12 MFMA
//    per stage (round-3: 12/24 with 16x16) -> LDS pipe 1152->768 cyc/CU/stage
//  * two read/MFMA sub-phases per stage (lgkmcnt(2) split) so the LDS burst
//    overlaps the MFMA cluster instead of draining before it.
// Swizzles: A rows 512B, 16B slot ^= row (low 3 bits); B rows 32B,
// chunk ^= code&1. Both patterns hit the 8-access/bank-quad minimum.
// LDS: 128K A + 32K B = 160K exactly; epilogue cand aliases B.
// ---------------------------------------------------------------------------
__launch_bounds__(512, 1)
__global__ void k_argmin(const _Float16* __restrict__ eh,
                         const _Float16* __restrict__ el,
                         const _Float16* __restrict__ cbh,
                         const _Float16* __restrict__ cbl,
                         const float* __restrict__ cbsq,
                         unsigned long long* __restrict__ packed) {
    __shared__ __align__(16) unsigned char smraw[163840];
    const _Float16* smH = (const _Float16*)smraw;

    const int t    = threadIdx.x;
    const int lane = t & 63;
    const int wave = t >> 6;          // 0..7
    const int wx   = wave & 3;        // code quarter (64 codes)
    const int wy   = wave >> 2;       // token half (64 tokens)
    const int lr32 = lane & 31;
    const int kh   = lane >> 5;       // k-half (8 ch) within BK=16

    const int n0 = blockIdx.x * TM;

    float minv[32];
    int   mini[32];
    #pragma unroll
    for (int e = 0; e < 32; ++e) { minv[e] = 3.402823466e38f; mini[e] = 0; }

    floatx16 acc[2][2];
    #pragma unroll
    for (int m = 0; m < 2; ++m)
        #pragma unroll
        for (int n = 0; n < 2; ++n)
            #pragma unroll
            for (int r = 0; r < 16; ++r) acc[m][n][r] = 0.f;

    // ---- B stage DMA: wave (hl = wave>>2, codes (wave&3)*64 + i*32).
    // Lane l writes dest byte l*16: code_off = l>>1, chunkbit = l&1.
    // Source pre-applies chunk ^= code&1.
    auto dmaB = [&](int buf, int sg) {
        const int cc = sg & 15;
        const int jt = sg >> 4;
        const int hl = wave >> 2;
        const _Float16* bsrc = hl ? cbl : cbh;
        const int cbase = jt * TN + (wave & 3) * 64;
        #pragma unroll
        for (int i = 0; i < 2; ++i) {
            const int code = cbase + i * 32 + (lane >> 1);
            const int sch  = cc * 16 + (((lane & 1) ^ (code & 1)) << 3);
            const _Float16* g = bsrc + (size_t)code * CH + sch;
            __builtin_amdgcn_global_load_lds(
                (guint_t*)g,
                (luint_t*)(smraw + 131072 + buf * 16384 + hl * 8192
                           + ((wave & 3) * 64 + i * 32) * 32),
                16, 0, 0);
        }
    };

    // ---- prologue: A tile -> LDS once. A layout: [hl][row128][512B row],
    // 16B slot ^= row (low 3 bits). Lane l: row = rowbase + (l>>5),
    // slot = l&31, source chunk qb = (slot&~7)|((slot^row)&7).
    {
        const int hl = wave >> 2;
        const _Float16* asrc = hl ? el : eh;
        const int rb = (wave & 3) * 32;
        #pragma unroll
        for (int i = 0; i < 16; ++i) {
            const int rowbase = rb + i * 2;
            const int row  = rowbase + (lane >> 5);
            const int slot = lane & 31;
            const int qb   = (slot & ~7) | ((slot ^ row) & 7);
            const _Float16* g = asrc + (size_t)(n0 + row) * CH + qb * 8;
            __builtin_amdgcn_global_load_lds(
                (guint_t*)g,
                (luint_t*)(smraw + hl * 65536 + rowbase * 512),
                16, 0, 0);
        }
    }
    dmaB(0, 0);
    asm volatile("s_waitcnt vmcnt(0)" ::: "memory");
    __syncthreads();

    float csq0 = 0.f, csq1 = 0.f;

    #pragma unroll 1
    for (int s = 0; s < NSTG; ++s) {
        const int cur = s & 1;
        const int cc  = s & 15;

        // issue next B stage (goes to buf^1; its readers finished before the
        // previous rendezvous)
        if (s + 1 < NSTG) dmaB(cur ^ 1, s + 1);

        // cbsq prefetch at jt start (used 15 stages later at the fold)
        if ((s & 15) == 0) {
            const int jb0 = (s >> 4) * TN + wx * 64 + lr32;
            csq0 = cbsq[jb0];
            csq1 = cbsq[jb0 + 32];
        }

        // ---- reads: fb (4), fa-m0 (2), fa-m1 (2) ----
        half8_t fbh0, fbh1, fbl0, fbl1, fah0, fal0, fah1, fal1;
        {
            const int bofs = 65536 + cur * 8192 + (wx * 64 + lr32) * 16
                           + ((kh ^ (lr32 & 1)) << 3);
            fbh0 = *(const half8_t*)&smH[bofs];
            fbh1 = *(const half8_t*)&smH[bofs + 512];
            fbl0 = *(const half8_t*)&smH[bofs + 4096];
            fbl1 = *(const half8_t*)&smH[bofs + 4096 + 512];

            const int qb   = cc * 2 + kh;
            const int row0 = wy * 64 + lr32;
            const int sl0  = (qb & ~7) | ((qb ^ row0) & 7);
            const int a0   = row0 * 256 + sl0 * 8;
            fah0 = *(const half8_t*)&smH[a0];
            fal0 = *(const half8_t*)&smH[32768 + a0];

            const int row1 = row0 + 32;
            const int sl1  = (qb & ~7) | ((qb ^ row1) & 7);
            const int a1   = row1 * 256 + sl1 * 8;
            fah1 = *(const half8_t*)&smH[a1];
            fal1 = *(const half8_t*)&smH[32768 + a1];
        }

        // ---- sub-phase 0: wait fb + fa-m0 (fa-m1 stays in flight) ----
        asm volatile("s_waitcnt lgkmcnt(2)" ::: "memory");
        __builtin_amdgcn_sched_barrier(0);
        __builtin_amdgcn_s_setprio(1);
        acc[0][0] = __builtin_amdgcn_mfma_f32_32x32x16_f16(fah0, fbh0, acc[0][0], 0, 0, 0);
        acc[0][1] = __builtin_amdgcn_mfma_f32_32x32x16_f16(fah0, fbh1, acc[0][1], 0, 0, 0);
        acc[0][0] = __builtin_amdgcn_mfma_f32_32x32x16_f16(fah0, fbl0, acc[0][0], 0, 0, 0);
        acc[0][1] = __builtin_amdgcn_mfma_f32_32x32x16_f16(fah0, fbl1, acc[0][1], 0, 0, 0);
        acc[0][0] = __builtin_amdgcn_mfma_f32_32x32x16_f16(fal0, fbh0, acc[0][0], 0, 0, 0);
        acc[0][1] = __builtin_amdgcn_mfma_f32_32x32x16_f16(fal0, fbh1, acc[0][1], 0, 0, 0);
        __builtin_amdgcn_s_setprio(0);

        // ---- sub-phase 1 ----
        asm volatile("s_waitcnt lgkmcnt(0)" ::: "memory");
        __builtin_amdgcn_sched_barrier(0);
        __builtin_amdgcn_s_setprio(1);
        acc[1][0] = __builtin_amdgcn_mfma_f32_32x32x16_f16(fah1, fbh0, acc[1][0], 0, 0, 0);
        acc[1][1] = __builtin_amdgcn_mfma_f32_32x32x16_f16(fah1, fbh1, acc[1][1], 0, 0, 0);
        acc[1][0] = __builtin_amdgcn_mfma_f32_32x32x16_f16(fah1, fbl0, acc[1][0], 0, 0, 0);
        acc[1][1] = __builtin_amdgcn_mfma_f32_32x32x16_f16(fah1, fbl1, acc[1][1], 0, 0, 0);
        acc[1][0] = __builtin_amdgcn_mfma_f32_32x32x16_f16(fal1, fbh0, acc[1][0], 0, 0, 0);
        acc[1][1] = __builtin_amdgcn_mfma_f32_32x32x16_f16(fal1, fbh1, acc[1][1], 0, 0, 0);
        __builtin_amdgcn_s_setprio(0);

        // ---- fold at jt end ----
        if ((s & 15) == 15) {
            const int jb = (s >> 4) * TN + wx * 64 + lr32;
            #pragma unroll
            for (int m = 0; m < 2; ++m) {
                #pragma unroll
                for (int r = 0; r < 16; ++r) {
                    const int e = m * 16 + r;
                    float s0 = csq0 - 2.0f * acc[m][0][r];
                    float s1 = csq1 - 2.0f * acc[m][1][r];
                    float sv = s0; int si = jb;
                    if (s1 < sv) { sv = s1; si = jb + 32; }
                    if (sv < minv[e]) { minv[e] = sv; mini[e] = si; }
                    acc[m][0][r] = 0.f;
                    acc[m][1][r] = 0.f;
                }
            }
        }

        // single rendezvous: my DMA(s+1) done; my reads of cur done above.
        asm volatile("s_waitcnt vmcnt(0)" ::: "memory");
        __builtin_amdgcn_sched_barrier(0);
        __builtin_amdgcn_s_barrier();
    }

    // ---- epilogue: cross-lane argmin (32-lane groups), cross-wx via LDS ----
    // C layout (HW-verified): col = lane&31, row = (reg&3)+8*(reg>>2)+4*kh.
    float* cand_v = (float*)(smraw + 131072);           // [4][128]
    int*   cand_i = (int*)(smraw + 131072 + 2048);      // [4][128]

    #pragma unroll
    for (int e = 0; e < 32; ++e) {
        float v = minv[e];
        int   x = mini[e];
        #pragma unroll
        for (int m = 1; m <= 16; m <<= 1) {
            float ov = __shfl_xor(v, m, 64);
            int   ox = __shfl_xor(x, m, 64);
            if (ov < v || (ov == v && ox < x)) { v = ov; x = ox; }
        }
        if (lr32 == 0) {
            int row = wy * 64 + (e >> 4) * 32 + kh * 4 + (e & 3)
                    + 8 * ((e >> 2) & 3);
            cand_v[wx * TM + row] = v;
            cand_i[wx * TM + row] = x;
        }
    }
    __syncthreads();

    if (t < TM) {
        float v0 = cand_v[t];          int i0 = cand_i[t];
        #pragma unroll
        for (int q = 1; q < 4; ++q) {
            float v1 = cand_v[q * TM + t]; int i1 = cand_i[q * TM + t];
            if (v1 < v0 || (v1 == v0 && i1 < i0)) { v0 = v1; i0 = i1; }
        }
        unsigned sb = __float_as_uint(v0);
        sb = (sb & 0x80000000u) ? ~sb : (sb | 0x80000000u);
        packed[n0 + t] = ((unsigned long long)sb << 32) | (unsigned)i0;
    }
}

// ---------------------------------------------------------------------------
// Kernel 3: gather + straight-through + loss partials + histogram
// ---------------------------------------------------------------------------
__global__ void k_gather(const float* __restrict__ emb,
                         const float* __restrict__ ces,
                         const float* __restrict__ usage,
                         const unsigned long long* __restrict__ packed,
                         float* __restrict__ out_eq,
                         float* __restrict__ codes_f,
                         int* __restrict__ hist,
                         float* __restrict__ partials) {
    int t = threadIdx.x;
    int wave = t >> 6, lane = t & 63;
    int n = blockIdx.x * 4 + wave;
    int k = (int)(packed[n] & 0xFFFFFFFFull);
    float uc = fmaxf(usage[k], 1e-5f);
    int c = lane * 4;

    float4 e = *(const float4*)&emb[(size_t)n * CH + c];
    float4 v = *(const float4*)&ces[(size_t)k * CH + c];
    float ea[4] = {e.x, e.y, e.z, e.w};
    float va[4] = {v.x, v.y, v.z, v.w};
    float eqa[4];
    float p = 0.0f;
    #pragma unroll
    for (int q = 0; q < 4; ++q) {
        float cb = va[q] / uc;
        float eq = ea[q] + (cb - ea[q]);
        eqa[q] = eq;
        float d = eq - ea[q];
        p += d * d;
    }
    *(float4*)&out_eq[(size_t)n * CH + c] =
        (float4){eqa[0], eqa[1], eqa[2], eqa[3]};

    #pragma unroll
    for (int off = 32; off; off >>= 1) p += __shfl_down(p, off);
    __shared__ float ps[4];
    if (lane == 0) {
        ps[wave] = p;
        codes_f[n] = (float)k;
        atomicAdd(&hist[k], 1);
    }
    __syncthreads();
    if (t == 0) partials[blockIdx.x] = ps[0] + ps[1] + ps[2] + ps[3];
}

// ---------------------------------------------------------------------------
// Kernel 4: exclusive prefix sum over hist -> offs, cursor (1 block)
// ---------------------------------------------------------------------------
__global__ void k_scan(const int* __restrict__ hist,
                       int* __restrict__ offs,
                       int* __restrict__ cursor) {
    __shared__ int bs[256];
    int t = threadIdx.x;
    int base = t * 32;
    int loc[32];
    int s = 0;
    #pragma unroll
    for (int i = 0; i < 32; ++i) { loc[i] = s; s += hist[base + i]; }
    int mysum = s;
    bs[t] = s;
    __syncthreads();
    for (int off = 1; off < 256; off <<= 1) {
        int v = (t >= off) ? bs[t - off] : 0;
        __syncthreads();
        bs[t] += v;
        __syncthreads();
    }
    int excl = bs[t] - mysum;
    #pragma unroll
    for (int i = 0; i < 32; ++i) {
        int o = excl + loc[i];
        offs[base + i]   = o;
        cursor[base + i] = o;
    }
}

// ---------------------------------------------------------------------------
// Kernel 5: scatter token ids into code-sorted buckets
// ---------------------------------------------------------------------------
__global__ void k_scatter(const unsigned long long* __restrict__ packed,
                          int* __restrict__ cursor,
                          int* __restrict__ bucket) {
    int n = blockIdx.x * 256 + threadIdx.x;
    int k = (int)(packed[n] & 0xFFFFFFFFull);
    int pos = atomicAdd(&cursor[k], 1);
    bucket[pos] = n;
}

// ---------------------------------------------------------------------------
// Kernel 6: per-code EMA (one BLOCK per code: coalesced 1KB row loads,
// thread t owns channel t, no atomics, no wave-serial latency chain)
// ---------------------------------------------------------------------------
__global__ void k_ema(const float* __restrict__ emb,
                      const float* __restrict__ ces,
                      const float* __restrict__ usage,
                      const int* __restrict__ hist,
                      const int* __restrict__ offs,
                      const int* __restrict__ bucket,
                      float* __restrict__ out_ces,
                      float* __restrict__ out_usage) {
    const float s = 0.01f;
    const float oms = 1.0f - s;
    int k = blockIdx.x, t = threadIdx.x;
    int start = offs[k], cnt = hist[k];
    float sum = 0.0f;
    #pragma unroll 2
    for (int i = 0; i < cnt; ++i) {
        int n = bucket[start + i];            // block-uniform (scalar) load
        sum += emb[(size_t)n * CH + t];       // coalesced row
    }
    out_ces[(size_t)k * CH + t] = oms * ces[(size_t)k * CH + t] + s * sum;
    if (t == 0) out_usage[k] = oms * usage[k] + s * (float)cnt;
}

// ---------------------------------------------------------------------------
// Kernel 7: reduce loss partials, mean over 2^23 elements
// ---------------------------------------------------------------------------
__global__ void k_final(const float* __restrict__ partials,
                        float* __restrict__ out_loss) {
    int t = threadIdx.x;
    float p = 0.0f;
    for (int i = t; i < NT / 4; i += 256) p += partials[i];
    #pragma unroll
    for (int off = 32; off; off >>= 1) p += __shfl_down(p, off);
    __shared__ float ps[4];
    if ((t & 63) == 0) ps[t >> 6] = p;
    __syncthreads();
    if (t == 0)
        out_loss[0] = (ps[0] + ps[1] + ps[2] + ps[3]) * (1.0f / 8388608.0f);
}

extern "C" void kernel_launch(void* const* d_in, const int* in_sizes, int n_in,
                              void* d_out, int out_size, void* d_ws, size_t ws_size,
                              hipStream_t stream) {
    const float* emb   = (const float*)d_in[0];  // [32768, 256]
    const float* usage = (const float*)d_in[1];  // [8192]
    const float* ces   = (const float*)d_in[2];  // [8192, 256]

    float* out      = (float*)d_out;
    float* o_codes  = out;                       // 32768
    float* o_eq     = out + NT;                  // 8388608
    float* o_loss   = o_eq + (size_t)NT * CH;    // 1
    float* o_usage  = o_loss + 1;                // 8192
    float* o_ces    = o_usage + KC;              // 2097152

    unsigned long long* packed = (unsigned long long*)d_ws;   // NT u64
    float* cbsq     = (float*)(packed + NT);                  // KC
    float* partials = cbsq + KC;                              // NT/4
    int* hist   = (int*)(partials + NT / 4);                  // KC
    int* offs   = hist + KC;                                  // KC
    int* cursor = offs + KC;                                  // KC
    int* bucket = cursor + KC;                                // NT
    _Float16* eh  = (_Float16*)(bucket + NT);                 // NT*CH
    _Float16* el  = eh + (size_t)NT * CH;
    _Float16* cbh = el + (size_t)NT * CH;                     // KC*CH
    _Float16* cbl = cbh + (size_t)KC * CH;

    k_prep<<<KC + NT * CH / 1024, 256, 0, stream>>>(
        usage, ces, emb, cbh, cbl, cbsq, eh, el, hist);
    k_argmin<<<NT / TM, 512, 0, stream>>>(eh, el, cbh, cbl, cbsq, packed);
    k_gather<<<NT / 4, 256, 0, stream>>>(emb, ces, usage, packed, o_eq,
                                         o_codes, hist, partials);
    k_scan<<<1, 256, 0, stream>>>(hist, offs, cursor);
    k_scatter<<<NT / 256, 256, 0, stream>>>(packed, cursor, bucket);
    k_ema<<<KC, 256, 0, stream>>>(emb, ces, usage, hist, offs, bucket,
                                  o_ces, o_usage);
    k_final<<<1, 256, 0, stream>>>(partials, o_loss);
}

// Round 7
// 578.848 us; speedup vs baseline: 1.1953x; 1.1554x over previous
//
#include <hip/hip_runtime.h>

#define CH 256
#define KC 8192
#define NT 32768

#define TPW 32         // tokens per wave (A panel in VGPRs)
#define JT  64         // codes per jt tile
#define JTS 64         // jt tiles per block (4096-code half)

typedef _Float16 half4_t __attribute__((ext_vector_type(4)));
typedef _Float16 half8_t __attribute__((ext_vector_type(8)));
typedef float floatx16 __attribute__((ext_vector_type(16)));

typedef __attribute__((address_space(1))) const unsigned int guint_t;
typedef __attribute__((address_space(3))) unsigned int luint_t;

// ---------------------------------------------------------------------------
// Kernel 1 (fused prep):
//  blocks [0, KC):   codebook row -> fp16 hi/lo + cbsq, zero hist, init packed
//  blocks [KC, ...): split embeddings fp32 -> fp16 hi/lo (1 float4/thread)
// ---------------------------------------------------------------------------
__global__ void k_prep(const float* __restrict__ usage,
                       const float* __restrict__ ces,
                       const float* __restrict__ emb,
                       _Float16* __restrict__ cbh,
                       _Float16* __restrict__ cbl,
                       float* __restrict__ cbsq,
                       _Float16* __restrict__ eh,
                       _Float16* __restrict__ el,
                       int* __restrict__ hist,
                       unsigned long long* __restrict__ packed) {
    int b = blockIdx.x, t = threadIdx.x;
    if (b < KC) {
        float uc = fmaxf(usage[b], 1e-5f);
        float v  = ces[b * CH + t];
        float cb = v / uc;
        _Float16 h = (_Float16)cb;
        cbh[b * CH + t] = h;
        cbl[b * CH + t] = (_Float16)(cb - (float)h);

        float p = cb * cb;
        #pragma unroll
        for (int off = 32; off; off >>= 1) p += __shfl_down(p, off);
        __shared__ float ps[4];
        int lane = t & 63, w = t >> 6;
        if (lane == 0) ps[w] = p;
        __syncthreads();
        if (t == 0) cbsq[b] = ps[0] + ps[1] + ps[2] + ps[3];
        if (t == 1) hist[b] = 0;
        int gid = b * CH + t;
        if (gid < NT) packed[gid] = 0xFFFFFFFFFFFFFFFFull;
    } else {
        int i = (b - KC) * 256 + t;      // float4 index
        float4 v = ((const float4*)emb)[i];
        float va[4] = {v.x, v.y, v.z, v.w};
        half4_t h, l;
        #pragma unroll
        for (int q = 0; q < 4; ++q) {
            _Float16 hh = (_Float16)va[q];
            h[q] = hh;
            l[q] = (_Float16)(va[q] - (float)hh);
        }
        ((half4_t*)eh)[i] = h;
        ((half4_t*)el)[i] = l;
    }
}

// ---------------------------------------------------------------------------
// Kernel 2: fp16-split argmin — A in registers, 32x32x16 MFMA,
// one barrier per 16 k-steps.
//  * grid (128 token-panels x 2 code-halves) = 256 blocks = 1/CU.
//  * 8 waves/block; wave owns 32 tokens: full A panel (32 tok x 256 ch,
//    hi+lo) = 128 VGPRs in 32x32-fragment layout (loaded once, per-lane
//    global). ZERO A LDS traffic.
//  * B: jt tile (64 codes x 256 ch hi+lo = 64 KiB) double-buffered in LDS,
//    staged k-major [ks16][h2][kh2][code64]x16B via 8 global_load_lds per
//    wave issued at jt start. K-major puts each lane-octet's ds_read_b128
//    on 8 consecutive 16B slots = 8 distinct bank quads (the rule the
//    round-3 zero-conflict measurement validates) -> conflict-free.
//  * __syncthreads() only at jt boundaries (64 total): within a jt the two
//    waves/SIMD slip phase, overlapping ds_read with MFMA.
//  * 32x32x16 MFMA operand/C layouts as validated by round 6 (passed).
//  * cross-half merge via packed-u64 atomicMin (round-0 proven).
// ---------------------------------------------------------------------------
__launch_bounds__(512, 2)
__global__ void k_argmin(const _Float16* __restrict__ eh,
                         const _Float16* __restrict__ el,
                         const _Float16* __restrict__ cbh,
                         const _Float16* __restrict__ cbl,
                         const float* __restrict__ cbsq,
                         unsigned long long* __restrict__ packed) {
    __shared__ __align__(16) char smB[131072];   // 2 x 64 KiB B dbuf

    const int t    = threadIdx.x;
    const int lane = t & 63;
    const int wave = t >> 6;          // 0..7: token group
    const int lr32 = lane & 31;       // fragment row/col
    const int kh   = lane >> 5;       // 8-ch half within a 16-ch k-step

    const int n0w = blockIdx.x * 256 + wave * TPW;   // this wave's tokens
    const int jq  = blockIdx.y * (JTS * JT);         // code half base

    // ---- A panel -> registers (once). 32x32 A-frag layout: lane holds
    // row lr32, halves ch = ks*16 + kh*8 .. +7. 16 k-steps x hi/lo.
    half8_t aregh[16], aregl[16];
    {
        const size_t rowoff = (size_t)(n0w + lr32) * CH + kh * 8;
        #pragma unroll
        for (int ks = 0; ks < 16; ++ks) {
            aregh[ks] = *(const half8_t*)(eh + rowoff + ks * 16);
            aregl[ks] = *(const half8_t*)(el + rowoff + ks * 16);
        }
    }

    // ---- B jt-tile DMA: 8 issues/wave; wave w stages planes (ks,h) =
    // p = w*4 + (d>>1), sub-half kh = d&1. Lane l -> code l.
    auto dmaB = [&](int buf, int jt) {
        const int jb = jq + jt * JT;
        #pragma unroll
        for (int d = 0; d < 8; ++d) {
            const int p   = wave * 4 + (d >> 1);   // plane 0..31
            const int ks  = p >> 1;
            const int h   = p & 1;
            const int sub = d & 1;                 // kh of the 16B chunk
            const _Float16* src = h ? cbl : cbh;
            const _Float16* g = src + (size_t)(jb + lane) * CH
                              + ks * 16 + sub * 8;
            __builtin_amdgcn_global_load_lds(
                (guint_t*)g,
                (luint_t*)(smB + buf * 65536 + ks * 4096 + h * 2048
                           + sub * 1024),
                16, 0, 0);
        }
    };

    float minv[16];
    int   mini[16];
    #pragma unroll
    for (int e = 0; e < 16; ++e) { minv[e] = 3.402823466e38f; mini[e] = 0; }

    floatx16 acc0, acc1;
    #pragma unroll
    for (int r = 0; r < 16; ++r) { acc0[r] = 0.f; acc1[r] = 0.f; }

    // prologue: jt 0 -> buf 0
    dmaB(0, 0);
    __syncthreads();

    // per-lane B fragment slot: [kh][code] -> byte (kh*64 + lr32)*16
    const int lslot = (kh * 64 + lr32) * 16;

    #pragma unroll 1
    for (int jt = 0; jt < JTS; ++jt) {
        const int buf = jt & 1;
        const int jb  = jq + jt * JT;

        // prefetch next jt into the other buffer (drained at the barrier)
        if (jt + 1 < JTS) dmaB(buf ^ 1, jt + 1);

        // cbsq for this jt (used at the fold; stays in flight over MFMA)
        const float csq0 = cbsq[jb + lr32];
        const float csq1 = cbsq[jb + 32 + lr32];

        // ---- 16 k-steps: 4 ds_read_b128 + 6 MFMA each ----
        const char* bbase = smB + buf * 65536 + lslot;
        #pragma unroll
        for (int ks = 0; ks < 16; ++ks) {
            const char* bp = bbase + ks * 4096;
            half8_t fbh0 = *(const half8_t*)(bp);          // h=0, nf=0
            half8_t fbh1 = *(const half8_t*)(bp + 512);    // h=0, nf=1
            half8_t fbl0 = *(const half8_t*)(bp + 2048);   // h=1, nf=0
            half8_t fbl1 = *(const half8_t*)(bp + 2560);   // h=1, nf=1
            acc0 = __builtin_amdgcn_mfma_f32_32x32x16_f16(aregh[ks], fbh0, acc0, 0, 0, 0);
            acc1 = __builtin_amdgcn_mfma_f32_32x32x16_f16(aregh[ks], fbh1, acc1, 0, 0, 0);
            acc0 = __builtin_amdgcn_mfma_f32_32x32x16_f16(aregh[ks], fbl0, acc0, 0, 0, 0);
            acc1 = __builtin_amdgcn_mfma_f32_32x32x16_f16(aregh[ks], fbl1, acc1, 0, 0, 0);
            acc0 = __builtin_amdgcn_mfma_f32_32x32x16_f16(aregl[ks], fbh0, acc0, 0, 0, 0);
            acc1 = __builtin_amdgcn_mfma_f32_32x32x16_f16(aregl[ks], fbh1, acc1, 0, 0, 0);
        }

        // ---- fold: d2 = cbsq - 2*dot. C layout (round-6 validated):
        // col = jb + nf*32 + lr32, row = (r&3) + 8*(r>>2) + 4*kh.
        #pragma unroll
        for (int r = 0; r < 16; ++r) {
            float s0 = csq0 - 2.0f * acc0[r];
            float s1 = csq1 - 2.0f * acc1[r];
            float sv = s0; int si = jb + lr32;
            if (s1 < sv) { sv = s1; si = jb + 32 + lr32; }
            if (sv < minv[r]) { minv[r] = sv; mini[r] = si; }
            acc0[r] = 0.f;
            acc1[r] = 0.f;
        }

        // jt rendezvous: drains my DMA (vmcnt 0) + all waves' reads of buf
        __syncthreads();
    }

    // ---- epilogue: reduce over the 32 codes held across lanes (lr32),
    // then atomicMin into packed (cross-code-half merge).
    #pragma unroll
    for (int r = 0; r < 16; ++r) {
        float v = minv[r];
        int   x = mini[r];
        #pragma unroll
        for (int m = 1; m <= 16; m <<= 1) {
            float ov = __shfl_xor(v, m, 64);
            int   ox = __shfl_xor(x, m, 64);
            if (ov < v || (ov == v && ox < x)) { v = ov; x = ox; }
        }
        if (lr32 == 0) {    // lanes 0 (kh=0) and 32 (kh=1)
            int tok = n0w + (r & 3) + 8 * (r >> 2) + 4 * kh;
            unsigned sb = __float_as_uint(v);
            sb = (sb & 0x80000000u) ? ~sb : (sb | 0x80000000u);
            unsigned long long key =
                ((unsigned long long)sb << 32) | (unsigned)x;
            atomicMin(&packed[tok], key);
        }
    }
}

// ---------------------------------------------------------------------------
// Kernel 3: gather + straight-through + loss partials + histogram
// ---------------------------------------------------------------------------
__global__ void k_gather(const float* __restrict__ emb,
                         const float* __restrict__ ces,
                         const float* __restrict__ usage,
                         const unsigned long long* __restrict__ packed,
                         float* __restrict__ out_eq,
                         float* __restrict__ codes_f,
                         int* __restrict__ hist,
                         float* __restrict__ partials) {
    int t = threadIdx.x;
    int wave = t >> 6, lane = t & 63;
    int n = blockIdx.x * 4 + wave;
    int k = (int)(packed[n] & 0xFFFFFFFFull);
    float uc = fmaxf(usage[k], 1e-5f);
    int c = lane * 4;

    float4 e = *(const float4*)&emb[(size_t)n * CH + c];
    float4 v = *(const float4*)&ces[(size_t)k * CH + c];
    float ea[4] = {e.x, e.y, e.z, e.w};
    float va[4] = {v.x, v.y, v.z, v.w};
    float eqa[4];
    float p = 0.0f;
    #pragma unroll
    for (int q = 0; q < 4; ++q) {
        float cb = va[q] / uc;
        float eq = ea[q] + (cb - ea[q]);
        eqa[q] = eq;
        float d = eq - ea[q];
        p += d * d;
    }
    *(float4*)&out_eq[(size_t)n * CH + c] =
        (float4){eqa[0], eqa[1], eqa[2], eqa[3]};

    #pragma unroll
    for (int off = 32; off; off >>= 1) p += __shfl_down(p, off);
    __shared__ float ps[4];
    if (lane == 0) {
        ps[wave] = p;
        codes_f[n] = (float)k;
        atomicAdd(&hist[k], 1);
    }
    __syncthreads();
    if (t == 0) partials[blockIdx.x] = ps[0] + ps[1] + ps[2] + ps[3];
}

// ---------------------------------------------------------------------------
// Kernel 4: exclusive prefix sum over hist -> offs, cursor (1 block)
// ---------------------------------------------------------------------------
__global__ void k_scan(const int* __restrict__ hist,
                       int* __restrict__ offs,
                       int* __restrict__ cursor) {
    __shared__ int bs[256];
    int t = threadIdx.x;
    int base = t * 32;
    int loc[32];
    int s = 0;
    #pragma unroll
    for (int i = 0; i < 32; ++i) { loc[i] = s; s += hist[base + i]; }
    int mysum = s;
    bs[t] = s;
    __syncthreads();
    for (int off = 1; off < 256; off <<= 1) {
        int v = (t >= off) ? bs[t - off] : 0;
        __syncthreads();
        bs[t] += v;
        __syncthreads();
    }
    int excl = bs[t] - mysum;
    #pragma unroll
    for (int i = 0; i < 32; ++i) {
        int o = excl + loc[i];
        offs[base + i]   = o;
        cursor[base + i] = o;
    }
}

// ---------------------------------------------------------------------------
// Kernel 5: scatter token ids into code-sorted buckets
// ---------------------------------------------------------------------------
__global__ void k_scatter(const unsigned long long* __restrict__ packed,
                          int* __restrict__ cursor,
                          int* __restrict__ bucket) {
    int n = blockIdx.x * 256 + threadIdx.x;
    int k = (int)(packed[n] & 0xFFFFFFFFull);
    int pos = atomicAdd(&cursor[k], 1);
    bucket[pos] = n;
}

// ---------------------------------------------------------------------------
// Kernel 6: per-code EMA (one BLOCK per code: coalesced 1KB row loads,
// thread t owns channel t, no atomics, no wave-serial latency chain)
// ---------------------------------------------------------------------------
__global__ void k_ema(const float* __restrict__ emb,
                      const float* __restrict__ ces,
                      const float* __restrict__ usage,
                      const int* __restrict__ hist,
                      const int* __restrict__ offs,
                      const int* __restrict__ bucket,
                      float* __restrict__ out_ces,
                      float* __restrict__ out_usage) {
    const float s = 0.01f;
    const float oms = 1.0f - s;
    int k = blockIdx.x, t = threadIdx.x;
    int start = offs[k], cnt = hist[k];
    float sum = 0.0f;
    #pragma unroll 2
    for (int i = 0; i < cnt; ++i) {
        int n = bucket[start + i];            // block-uniform (scalar) load
        sum += emb[(size_t)n * CH + t];       // coalesced row
    }
    out_ces[(size_t)k * CH + t] = oms * ces[(size_t)k * CH + t] + s * sum;
    if (t == 0) out_usage[k] = oms * usage[k] + s * (float)cnt;
}

// ---------------------------------------------------------------------------
// Kernel 7: reduce loss partials, mean over 2^23 elements
// ---------------------------------------------------------------------------
__global__ void k_final(const float* __restrict__ partials,
                        float* __restrict__ out_loss) {
    int t = threadIdx.x;
    float p = 0.0f;
    for (int i = t; i < NT / 4; i += 256) p += partials[i];
    #pragma unroll
    for (int off = 32; off; off >>= 1) p += __shfl_down(p, off);
    __shared__ float ps[4];
    if ((t & 63) == 0) ps[t >> 6] = p;
    __syncthreads();
    if (t == 0)
        out_loss[0] = (ps[0] + ps[1] + ps[2] + ps[3]) * (1.0f / 8388608.0f);
}

extern "C" void kernel_launch(void* const* d_in, const int* in_sizes, int n_in,
                              void* d_out, int out_size, void* d_ws, size_t ws_size,
                              hipStream_t stream) {
    const float* emb   = (const float*)d_in[0];  // [32768, 256]
    const float* usage = (const float*)d_in[1];  // [8192]
    const float* ces   = (const float*)d_in[2];  // [8192, 256]

    float* out      = (float*)d_out;
    float* o_codes  = out;                       // 32768
    float* o_eq     = out + NT;                  // 8388608
    float* o_loss   = o_eq + (size_t)NT * CH;    // 1
    float* o_usage  = o_loss + 1;                // 8192
    float* o_ces    = o_usage + KC;              // 2097152

    unsigned long long* packed = (unsigned long long*)d_ws;   // NT u64
    float* cbsq     = (float*)(packed + NT);                  // KC
    float* partials = cbsq + KC;                              // NT/4
    int* hist   = (int*)(partials + NT / 4);                  // KC
    int* offs   = hist + KC;                                  // KC
    int* cursor = offs + KC;                                  // KC
    int* bucket = cursor + KC;                                // NT
    _Float16* eh  = (_Float16*)(bucket + NT);                 // NT*CH
    _Float16* el  = eh + (size_t)NT * CH;
    _Float16* cbh = el + (size_t)NT * CH;                     // KC*CH
    _Float16* cbl = cbh + (size_t)KC * CH;

    k_prep<<<KC + NT * CH / 1024, 256, 0, stream>>>(
        usage, ces, emb, cbh, cbl, cbsq, eh, el, hist, packed);
    dim3 agrid(NT / 256, 2);
    k_argmin<<<agrid, 512, 0, stream>>>(eh, el, cbh, cbl, cbsq, packed);
    k_gather<<<NT / 4, 256, 0, stream>>>(emb, ces, usage, packed, o_eq,
                                         o_codes, hist, partials);
    k_scan<<<1, 256, 0, stream>>>(hist, offs, cursor);
    k_scatter<<<NT / 256, 256, 0, stream>>>(packed, cursor, bucket);
    k_ema<<<KC, 256, 0, stream>>>(emb, ces, usage, hist, offs, bucket,
                                  o_ces, o_usage);
    k_final<<<1, 256, 0, stream>>>(partials, o_loss);
}

// Round 8
// 576.282 us; speedup vs baseline: 1.2006x; 1.0045x over previous
//
#include <hip/hip_runtime.h>

#define CH 256
#define KC 8192
#define NT 32768

#define TPW 32         // tokens per wave (A panel in VGPRs)
#define JT  64         // codes per jt tile
#define JTS 64         // jt tiles per block (4096-code half)

typedef _Float16 half4_t __attribute__((ext_vector_type(4)));
typedef _Float16 half8_t __attribute__((ext_vector_type(8)));
typedef float floatx16 __attribute__((ext_vector_type(16)));

typedef __attribute__((address_space(1))) const unsigned int guint_t;
typedef __attribute__((address_space(3))) unsigned int luint_t;

// ---------------------------------------------------------------------------
// Kernel 1 (fused prep):
//  blocks [0, KC):   codebook row -> fp16 hi/lo + cbsq, zero hist, init packed
//  blocks [KC, ...): split embeddings fp32 -> fp16 hi/lo (1 float4/thread)
// ---------------------------------------------------------------------------
__global__ void k_prep(const float* __restrict__ usage,
                       const float* __restrict__ ces,
                       const float* __restrict__ emb,
                       _Float16* __restrict__ cbh,
                       _Float16* __restrict__ cbl,
                       float* __restrict__ cbsq,
                       _Float16* __restrict__ eh,
                       _Float16* __restrict__ el,
                       int* __restrict__ hist,
                       unsigned long long* __restrict__ packed) {
    int b = blockIdx.x, t = threadIdx.x;
    if (b < KC) {
        float uc = fmaxf(usage[b], 1e-5f);
        float v  = ces[b * CH + t];
        float cb = v / uc;
        _Float16 h = (_Float16)cb;
        cbh[b * CH + t] = h;
        cbl[b * CH + t] = (_Float16)(cb - (float)h);

        float p = cb * cb;
        #pragma unroll
        for (int off = 32; off; off >>= 1) p += __shfl_down(p, off);
        __shared__ float ps[4];
        int lane = t & 63, w = t >> 6;
        if (lane == 0) ps[w] = p;
        __syncthreads();
        if (t == 0) cbsq[b] = ps[0] + ps[1] + ps[2] + ps[3];
        if (t == 1) hist[b] = 0;
        int gid = b * CH + t;
        if (gid < NT) packed[gid] = 0xFFFFFFFFFFFFFFFFull;
    } else {
        int i = (b - KC) * 256 + t;      // float4 index
        float4 v = ((const float4*)emb)[i];
        float va[4] = {v.x, v.y, v.z, v.w};
        half4_t h, l;
        #pragma unroll
        for (int q = 0; q < 4; ++q) {
            _Float16 hh = (_Float16)va[q];
            h[q] = hh;
            l[q] = (_Float16)(va[q] - (float)hh);
        }
        ((half4_t*)eh)[i] = h;
        ((half4_t*)el)[i] = l;
    }
}

// ---------------------------------------------------------------------------
// Kernel 2: fp16-split argmin — round-7 structure (378 µs, 0 conflicts) +
// forced LDS/MFMA overlap:
//  * explicit B-fragment register double-buffer: ks+1's 4 ds_read_b128
//    issue BEFORE ks's 6 MFMA (static p/q register sets),
//  * wave-parity ks-rotation (odd waves run 8..15,0..7; two compile-time
//    unrolled variants keep A-register indices static) so half the waves
//    read while half MFMA even straight after the jt barrier,
//  * s_setprio(1) around the MFMA cluster (waves now role-diverge).
// Everything else identical to round 7: A panel (32 tok, hi+lo) in 128
// VGPRs; B jt tile 64 KiB k-major double-buffered via global_load_lds;
// one __syncthreads per jt; 32x32x16 MFMA; packed-u64 atomicMin merge.
// ---------------------------------------------------------------------------
__launch_bounds__(512, 2)
__global__ void k_argmin(const _Float16* __restrict__ eh,
                         const _Float16* __restrict__ el,
                         const _Float16* __restrict__ cbh,
                         const _Float16* __restrict__ cbl,
                         const float* __restrict__ cbsq,
                         unsigned long long* __restrict__ packed) {
    __shared__ __align__(16) char smB[131072];   // 2 x 64 KiB B dbuf

    const int t    = threadIdx.x;
    const int lane = t & 63;
    const int wave = t >> 6;          // 0..7: token group
    const int lr32 = lane & 31;       // fragment row/col
    const int kh   = lane >> 5;       // 8-ch half within a 16-ch k-step

    const int n0w = blockIdx.x * 256 + wave * TPW;   // this wave's tokens
    const int jq  = blockIdx.y * (JTS * JT);         // code half base

    // ---- A panel -> registers (once). 32x32 A-frag layout: lane holds
    // row lr32, halves ch = ks*16 + kh*8 .. +7. 16 k-steps x hi/lo.
    half8_t aregh[16], aregl[16];
    {
        const size_t rowoff = (size_t)(n0w + lr32) * CH + kh * 8;
        #pragma unroll
        for (int ks = 0; ks < 16; ++ks) {
            aregh[ks] = *(const half8_t*)(eh + rowoff + ks * 16);
            aregl[ks] = *(const half8_t*)(el + rowoff + ks * 16);
        }
    }

    // ---- B jt-tile DMA: 8 issues/wave; wave w stages planes (ks,h) =
    // p = w*4 + (d>>1), sub-half kh = d&1. Lane l -> code l.
    auto dmaB = [&](int buf, int jt) {
        const int jb = jq + jt * JT;
        #pragma unroll
        for (int d = 0; d < 8; ++d) {
            const int p   = wave * 4 + (d >> 1);   // plane 0..31
            const int ks  = p >> 1;
            const int h   = p & 1;
            const int sub = d & 1;                 // kh of the 16B chunk
            const _Float16* src = h ? cbl : cbh;
            const _Float16* g = src + (size_t)(jb + lane) * CH
                              + ks * 16 + sub * 8;
            __builtin_amdgcn_global_load_lds(
                (guint_t*)g,
                (luint_t*)(smB + buf * 65536 + ks * 4096 + h * 2048
                           + sub * 1024),
                16, 0, 0);
        }
    };

    float minv[16];
    int   mini[16];
    #pragma unroll
    for (int e = 0; e < 16; ++e) { minv[e] = 3.402823466e38f; mini[e] = 0; }

    floatx16 acc0, acc1;
    #pragma unroll
    for (int r = 0; r < 16; ++r) { acc0[r] = 0.f; acc1[r] = 0.f; }

    // prologue: jt 0 -> buf 0
    dmaB(0, 0);
    __syncthreads();

    // per-lane B fragment slot: [kh][code] -> byte (kh*64 + lr32)*16
    const int lslot = (kh * 64 + lr32) * 16;
    const int par   = wave & 1;       // phase stagger

#define MFMA6(KE, B0, B1, B2, B3)                                            \
    acc0 = __builtin_amdgcn_mfma_f32_32x32x16_f16(aregh[KE], B0, acc0, 0,0,0); \
    acc1 = __builtin_amdgcn_mfma_f32_32x32x16_f16(aregh[KE], B1, acc1, 0,0,0); \
    acc0 = __builtin_amdgcn_mfma_f32_32x32x16_f16(aregh[KE], B2, acc0, 0,0,0); \
    acc1 = __builtin_amdgcn_mfma_f32_32x32x16_f16(aregh[KE], B3, acc1, 0,0,0); \
    acc0 = __builtin_amdgcn_mfma_f32_32x32x16_f16(aregl[KE], B0, acc0, 0,0,0); \
    acc1 = __builtin_amdgcn_mfma_f32_32x32x16_f16(aregl[KE], B1, acc1, 0,0,0);

#define PRIME(KS, R)                                                         \
    { const char* bp_ = bbase + (KS) * 4096;                                 \
      R##0 = *(const half8_t*)(bp_);                                         \
      R##1 = *(const half8_t*)(bp_ + 512);                                   \
      R##2 = *(const half8_t*)(bp_ + 2048);                                  \
      R##3 = *(const half8_t*)(bp_ + 2560); }

#define JTSTEP(KS, CUR, NXT, LAST)                                           \
    { if (!(LAST)) PRIME((((KS) + 1) & 15), NXT)                             \
      __builtin_amdgcn_s_setprio(1);                                         \
      MFMA6((KS), CUR##0, CUR##1, CUR##2, CUR##3)                            \
      __builtin_amdgcn_s_setprio(0); }

    #pragma unroll 1
    for (int jt = 0; jt < JTS; ++jt) {
        const int buf = jt & 1;
        const int jb  = jq + jt * JT;

        // prefetch next jt into the other buffer (drained at the barrier)
        if (jt + 1 < JTS) dmaB(buf ^ 1, jt + 1);

        // cbsq for this jt (in flight over the whole jt)
        const float csq0 = cbsq[jb + lr32];
        const float csq1 = cbsq[jb + 32 + lr32];

        const char* bbase = smB + buf * 65536 + lslot;
        half8_t p0, p1, p2, p3, q0, q1, q2, q3;

        if (par == 0) {
            PRIME(0, p)
            JTSTEP(0,  p, q, 0) JTSTEP(1,  q, p, 0)
            JTSTEP(2,  p, q, 0) JTSTEP(3,  q, p, 0)
            JTSTEP(4,  p, q, 0) JTSTEP(5,  q, p, 0)
            JTSTEP(6,  p, q, 0) JTSTEP(7,  q, p, 0)
            JTSTEP(8,  p, q, 0) JTSTEP(9,  q, p, 0)
            JTSTEP(10, p, q, 0) JTSTEP(11, q, p, 0)
            JTSTEP(12, p, q, 0) JTSTEP(13, q, p, 0)
            JTSTEP(14, p, q, 0) JTSTEP(15, q, p, 1)
        } else {
            PRIME(8, p)
            JTSTEP(8,  p, q, 0) JTSTEP(9,  q, p, 0)
            JTSTEP(10, p, q, 0) JTSTEP(11, q, p, 0)
            JTSTEP(12, p, q, 0) JTSTEP(13, q, p, 0)
            JTSTEP(14, p, q, 0) JTSTEP(15, q, p, 0)
            JTSTEP(0,  p, q, 0) JTSTEP(1,  q, p, 0)
            JTSTEP(2,  p, q, 0) JTSTEP(3,  q, p, 0)
            JTSTEP(4,  p, q, 0) JTSTEP(5,  q, p, 0)
            JTSTEP(6,  p, q, 0) JTSTEP(7,  q, p, 1)
        }

        // ---- fold: d2 = cbsq - 2*dot. C layout (validated):
        // col = jb + nf*32 + lr32, row = (r&3) + 8*(r>>2) + 4*kh.
        #pragma unroll
        for (int r = 0; r < 16; ++r) {
            float s0 = csq0 - 2.0f * acc0[r];
            float s1 = csq1 - 2.0f * acc1[r];
            float sv = s0; int si = jb + lr32;
            if (s1 < sv) { sv = s1; si = jb + 32 + lr32; }
            if (sv < minv[r]) { minv[r] = sv; mini[r] = si; }
            acc0[r] = 0.f;
            acc1[r] = 0.f;
        }

        // jt rendezvous: drains my DMA (vmcnt 0) + all waves' reads of buf
        __syncthreads();
    }
#undef JTSTEP
#undef PRIME
#undef MFMA6

    // ---- epilogue: reduce over the 32 codes held across lanes (lr32),
    // then atomicMin into packed (cross-code-half merge).
    #pragma unroll
    for (int r = 0; r < 16; ++r) {
        float v = minv[r];
        int   x = mini[r];
        #pragma unroll
        for (int m = 1; m <= 16; m <<= 1) {
            float ov = __shfl_xor(v, m, 64);
            int   ox = __shfl_xor(x, m, 64);
            if (ov < v || (ov == v && ox < x)) { v = ov; x = ox; }
        }
        if (lr32 == 0) {    // lanes 0 (kh=0) and 32 (kh=1)
            int tok = n0w + (r & 3) + 8 * (r >> 2) + 4 * kh;
            unsigned sb = __float_as_uint(v);
            sb = (sb & 0x80000000u) ? ~sb : (sb | 0x80000000u);
            unsigned long long key =
                ((unsigned long long)sb << 32) | (unsigned)x;
            atomicMin(&packed[tok], key);
        }
    }
}

// ---------------------------------------------------------------------------
// Kernel 3: gather + straight-through + loss partials + histogram
// ---------------------------------------------------------------------------
__global__ void k_gather(const float* __restrict__ emb,
                         const float* __restrict__ ces,
                         const float* __restrict__ usage,
                         const unsigned long long* __restrict__ packed,
                         float* __restrict__ out_eq,
                         float* __restrict__ codes_f,
                         int* __restrict__ hist,
                         float* __restrict__ partials) {
    int t = threadIdx.x;
    int wave = t >> 6, lane = t & 63;
    int n = blockIdx.x * 4 + wave;
    int k = (int)(packed[n] & 0xFFFFFFFFull);
    float uc = fmaxf(usage[k], 1e-5f);
    int c = lane * 4;

    float4 e = *(const float4*)&emb[(size_t)n * CH + c];
    float4 v = *(const float4*)&ces[(size_t)k * CH + c];
    float ea[4] = {e.x, e.y, e.z, e.w};
    float va[4] = {v.x, v.y, v.z, v.w};
    float eqa[4];
    float p = 0.0f;
    #pragma unroll
    for (int q = 0; q < 4; ++q) {
        float cb = va[q] / uc;
        float eq = ea[q] + (cb - ea[q]);
        eqa[q] = eq;
        float d = eq - ea[q];
        p += d * d;
    }
    *(float4*)&out_eq[(size_t)n * CH + c] =
        (float4){eqa[0], eqa[1], eqa[2], eqa[3]};

    #pragma unroll
    for (int off = 32; off; off >>= 1) p += __shfl_down(p, off);
    __shared__ float ps[4];
    if (lane == 0) {
        ps[wave] = p;
        codes_f[n] = (float)k;
        atomicAdd(&hist[k], 1);
    }
    __syncthreads();
    if (t == 0) partials[blockIdx.x] = ps[0] + ps[1] + ps[2] + ps[3];
}

// ---------------------------------------------------------------------------
// Kernel 4: exclusive prefix sum over hist -> offs, cursor (1 block)
// ---------------------------------------------------------------------------
__global__ void k_scan(const int* __restrict__ hist,
                       int* __restrict__ offs,
                       int* __restrict__ cursor) {
    __shared__ int bs[256];
    int t = threadIdx.x;
    int base = t * 32;
    int loc[32];
    int s = 0;
    #pragma unroll
    for (int i = 0; i < 32; ++i) { loc[i] = s; s += hist[base + i]; }
    int mysum = s;
    bs[t] = s;
    __syncthreads();
    for (int off = 1; off < 256; off <<= 1) {
        int v = (t >= off) ? bs[t - off] : 0;
        __syncthreads();
        bs[t] += v;
        __syncthreads();
    }
    int excl = bs[t] - mysum;
    #pragma unroll
    for (int i = 0; i < 32; ++i) {
        int o = excl + loc[i];
        offs[base + i]   = o;
        cursor[base + i] = o;
    }
}

// ---------------------------------------------------------------------------
// Kernel 5: scatter token ids into code-sorted buckets
// ---------------------------------------------------------------------------
__global__ void k_scatter(const unsigned long long* __restrict__ packed,
                          int* __restrict__ cursor,
                          int* __restrict__ bucket) {
    int n = blockIdx.x * 256 + threadIdx.x;
    int k = (int)(packed[n] & 0xFFFFFFFFull);
    int pos = atomicAdd(&cursor[k], 1);
    bucket[pos] = n;
}

// ---------------------------------------------------------------------------
// Kernel 6: per-code EMA (one BLOCK per code: coalesced 1KB row loads,
// thread t owns channel t, no atomics, no wave-serial latency chain)
// ---------------------------------------------------------------------------
__global__ void k_ema(const float* __restrict__ emb,
                      const float* __restrict__ ces,
                      const float* __restrict__ usage,
                      const int* __restrict__ hist,
                      const int* __restrict__ offs,
                      const int* __restrict__ bucket,
                      float* __restrict__ out_ces,
                      float* __restrict__ out_usage) {
    const float s = 0.01f;
    const float oms = 1.0f - s;
    int k = blockIdx.x, t = threadIdx.x;
    int start = offs[k], cnt = hist[k];
    float sum = 0.0f;
    #pragma unroll 2
    for (int i = 0; i < cnt; ++i) {
        int n = bucket[start + i];            // block-uniform (scalar) load
        sum += emb[(size_t)n * CH + t];       // coalesced row
    }
    out_ces[(size_t)k * CH + t] = oms * ces[(size_t)k * CH + t] + s * sum;
    if (t == 0) out_usage[k] = oms * usage[k] + s * (float)cnt;
}

// ---------------------------------------------------------------------------
// Kernel 7: reduce loss partials, mean over 2^23 elements
// ---------------------------------------------------------------------------
__global__ void k_final(const float* __restrict__ partials,
                        float* __restrict__ out_loss) {
    int t = threadIdx.x;
    float p = 0.0f;
    for (int i = t; i < NT / 4; i += 256) p += partials[i];
    #pragma unroll
    for (int off = 32; off; off >>= 1) p += __shfl_down(p, off);
    __shared__ float ps[4];
    if ((t & 63) == 0) ps[t >> 6] = p;
    __syncthreads();
    if (t == 0)
        out_loss[0] = (ps[0] + ps[1] + ps[2] + ps[3]) * (1.0f / 8388608.0f);
}

extern "C" void kernel_launch(void* const* d_in, const int* in_sizes, int n_in,
                              void* d_out, int out_size, void* d_ws, size_t ws_size,
                              hipStream_t stream) {
    const float* emb   = (const float*)d_in[0];  // [32768, 256]
    const float* usage = (const float*)d_in[1];  // [8192]
    const float* ces   = (const float*)d_in[2];  // [8192, 256]

    float* out      = (float*)d_out;
    float* o_codes  = out;                       // 32768
    float* o_eq     = out + NT;                  // 8388608
    float* o_loss   = o_eq + (size_t)NT * CH;    // 1
    float* o_usage  = o_loss + 1;                // 8192
    float* o_ces    = o_usage + KC;              // 2097152

    unsigned long long* packed = (unsigned long long*)d_ws;   // NT u64
    float* cbsq     = (float*)(packed + NT);                  // KC
    float* partials = cbsq + KC;                              // NT/4
    int* hist   = (int*)(partials + NT / 4);                  // KC
    int* offs   = hist + KC;                                  // KC
    int* cursor = offs + KC;                                  // KC
    int* bucket = cursor + KC;                                // NT
    _Float16* eh  = (_Float16*)(bucket + NT);                 // NT*CH
    _Float16* el  = eh + (size_t)NT * CH;
    _Float16* cbh = el + (size_t)NT * CH;                     // KC*CH
    _Float16* cbl = cbh + (size_t)KC * CH;

    k_prep<<<KC + NT * CH / 1024, 256, 0, stream>>>(
        usage, ces, emb, cbh, cbl, cbsq, eh, el, hist, packed);
    dim3 agrid(NT / 256, 2);
    k_argmin<<<agrid, 512, 0, stream>>>(eh, el, cbh, cbl, cbsq, packed);
    k_gather<<<NT / 4, 256, 0, stream>>>(emb, ces, usage, packed, o_eq,
                                         o_codes, hist, partials);
    k_scan<<<1, 256, 0, stream>>>(hist, offs, cursor);
    k_scatter<<<NT / 256, 256, 0, stream>>>(packed, cursor, bucket);
    k_ema<<<KC, 256, 0, stream>>>(emb, ces, usage, hist, offs, bucket,
                                  o_ces, o_usage);
    k_final<<<1, 256, 0, stream>>>(partials, o_loss);
}